// Round 2
// baseline (57.113 us; speedup 1.0000x reference)
//
#include <hip/hip_runtime.h>
#include <math.h>

#define IMG_W 512
#define OW 113

__device__ __forceinline__ float max4f(float4 v) { return fmaxf(fmaxf(v.x, v.y), fmaxf(v.z, v.w)); }
__device__ __forceinline__ float min4f(float4 v) { return fminf(fminf(v.x, v.y), fminf(v.z, v.w)); }

// One block = one 4x4 patch of windows (grid 29x29 = 841 blocks, 512 threads).
// Rationale vs the 8x8-patch version: 225 blocks on 256 CUs gave <=1 block/CU,
// so the per-block critical path (global-load latency + 4 barrier convoys) was
// fully exposed — adding waves to the SAME block didn't help (all waves share
// the barriers). 841 small blocks (~16 KB LDS each) co-reside 3-4 per CU, so
// one block's barrier stalls hide under another block's loads. Each phase now
// fits in a single thread-pass, and the horizontal window sums run on disjoint
// thread ranges fully parallel with the pools.
__global__ __launch_bounds__(512) void fd_fused(const float* __restrict__ X,
                                                float* __restrict__ out) {
    const int bi = blockIdx.x / 29;
    const int bj = blockIdx.x - bi * 29;
    const int t  = threadIdx.x;

    __shared__ float2 tmm[19][20];          // (max,min) of 4x4 px tiles (19x19 halo)
    __shared__ float2 p8[18][20];           // 8x8 px pools
    __shared__ float2 p16[16][20];          // 16x16
    __shared__ float2 p32[12][13];          // 32x32
    __shared__ float df4[19][21], df8[18][21], df16[16][21], df32[12][13];
    __shared__ float h4[19][5], h8[18][5], h16[16][5];   // horizontal window sums (4 cols)

    // ---- stage: per-4x4-tile max/min for the 19x19 halo (361 items, 1 pass) ----
    if (t < 19 * 19) {
        const int lr = t / 19, lc = t - lr * 19;
        const int gr = min(bi * 4 + lr, 127);   // clamped entries feed only guarded windows
        const int gc = min(bj * 4 + lc, 127);
        const float* p = X + (gr * 4) * IMG_W + gc * 4;
        float4 a = *(const float4*)(p);
        float4 b = *(const float4*)(p + IMG_W);
        float4 c = *(const float4*)(p + 2 * IMG_W);
        float4 d = *(const float4*)(p + 3 * IMG_W);
        float mx = fmaxf(fmaxf(max4f(a), max4f(b)), fmaxf(max4f(c), max4f(d)));
        float mn = fminf(fminf(min4f(a), min4f(b)), fminf(min4f(c), min4f(d)));
        tmm[lr][lc] = make_float2(mx, mn);
        df4[lr][lc] = mx - mn;
    }
    __syncthreads();

    // ---- P8 pool (18x18 = 324 on t<324) + h4 sums (19x4 = 76 on t in [400,476)) ----
    if (t < 18 * 18) {
        const int lr = t / 18, lc = t - lr * 18;
        float2 q00 = tmm[lr][lc],     q01 = tmm[lr][lc + 1];
        float2 q10 = tmm[lr + 1][lc], q11 = tmm[lr + 1][lc + 1];
        float x = fmaxf(fmaxf(q00.x, q01.x), fmaxf(q10.x, q11.x));
        float n = fminf(fminf(q00.y, q01.y), fminf(q10.y, q11.y));
        p8[lr][lc] = make_float2(x, n);
        df8[lr][lc] = x - n;
    } else if (t >= 400 && t < 400 + 19 * 4) {
        const int u = t - 400;
        const int r = u >> 2, wj = u & 3;
        float s = 0.f;
        #pragma unroll
        for (int b = 0; b < 16; ++b) s += df4[r][wj + b];
        h4[r][wj] = s;
    }
    __syncthreads();

    // ---- P16 pool (16x16 = 256 on t<256) + h8 (18x4 = 72 on t in [256,328)) ----
    if (t < 256) {
        const int lr = t >> 4, lc = t & 15;
        float2 q00 = p8[lr][lc],     q01 = p8[lr][lc + 2];
        float2 q10 = p8[lr + 2][lc], q11 = p8[lr + 2][lc + 2];
        float x = fmaxf(fmaxf(q00.x, q01.x), fmaxf(q10.x, q11.x));
        float n = fminf(fminf(q00.y, q01.y), fminf(q10.y, q11.y));
        p16[lr][lc] = make_float2(x, n);
        df16[lr][lc] = x - n;
    } else if (t < 256 + 18 * 4) {
        const int u = t - 256;
        const int r = u >> 2, wj = u & 3;
        float s = 0.f;
        #pragma unroll
        for (int b = 0; b < 8; ++b) s += df8[r][wj + 2 * b];
        h8[r][wj] = s;
    }
    __syncthreads();

    // ---- P32 pool (12x12 = 144 on t<144) + h16 (16x4 = 64 on t in [144,208)) ----
    if (t < 12 * 12) {
        const int lr = t / 12, lc = t - lr * 12;
        float2 q00 = p16[lr][lc],     q01 = p16[lr][lc + 4];
        float2 q10 = p16[lr + 4][lc], q11 = p16[lr + 4][lc + 4];
        float x = fmaxf(fmaxf(q00.x, q01.x), fmaxf(q10.x, q11.x));
        float n = fminf(fminf(q00.y, q01.y), fminf(q10.y, q11.y));
        p32[lr][lc] = make_float2(x, n);
        df32[lr][lc] = x - n;
    } else if (t < 144 + 16 * 4) {
        const int u = t - 144;
        const int r = u >> 2, wj = u & 3;
        float s = 0.f;
        #pragma unroll
        for (int b = 0; b < 4; ++b) s += df16[r][wj + 4 * b];
        h16[r][wj] = s;
    }
    __syncthreads();

    // ---- final: 4 threads per window, 16 windows -> 64 threads (1 wave) ----
    if (t < 64) {
        const int q  = t >> 2;        // window 0..15
        const int pp = t & 3;         // part 0..3
        const int wi = q >> 2, wj = q & 3;

        float d4 = h4[wi + 4 * pp][wj]     + h4[wi + 4 * pp + 1][wj]
                 + h4[wi + 4 * pp + 2][wj] + h4[wi + 4 * pp + 3][wj];
        float d8 = h8[wi + 4 * pp][wj] + h8[wi + 4 * pp + 2][wj];
        float d16 = h16[wi + 4 * pp][wj];
        float d32 = 0.f, d64 = 0.f;
        if (pp < 2) d32 = df32[wi + 8 * pp][wj] + df32[wi + 8 * pp][wj + 8];
        if (pp == 0) {
            float2 a0 = p32[wi][wj],     a1 = p32[wi][wj + 8];
            float2 a2 = p32[wi + 8][wj], a3 = p32[wi + 8][wj + 8];
            d64 = fmaxf(fmaxf(a0.x, a1.x), fmaxf(a2.x, a3.x))
                - fminf(fminf(a0.y, a1.y), fminf(a2.y, a3.y));
        }

        d4  += __shfl_down(d4,  2, 64);  d4  += __shfl_down(d4,  1, 64);
        d8  += __shfl_down(d8,  2, 64);  d8  += __shfl_down(d8,  1, 64);
        d16 += __shfl_down(d16, 2, 64);  d16 += __shfl_down(d16, 1, 64);
        d32 += __shfl_down(d32, 1, 64);  // p0 += p1 (p2/p3 are 0)

        if (pp == 0) {
            const int gwi = bi * 4 + wi;
            const int gwj = bj * 4 + wj;
            if (gwi < OW && gwj < OW) {
                // fd = -(sum_i log2(s_i) * log2(d_i)) / sum_i log2(s_i)^2
                // ln-form's ln2 factors cancel against 90*ln2: native v_log_f32.
                const float num = 6.f * __log2f(d64) + 5.f * __log2f(d32)
                                + 4.f * __log2f(d16) + 3.f * __log2f(d8)
                                + 2.f * __log2f(d4);
                out[gwi * OW + gwj] = -num / 90.0f;
            }
        }
    }
}

extern "C" void kernel_launch(void* const* d_in, const int* in_sizes, int n_in,
                              void* d_out, int out_size, void* d_ws, size_t ws_size,
                              hipStream_t stream) {
    const float* X = (const float*)d_in[0];
    float* out = (float*)d_out;
    fd_fused<<<29 * 29, 512, 0, stream>>>(X, out);
}